// Round 4
// baseline (324.214 us; speedup 1.0000x reference)
//
#include <hip/hip_runtime.h>
#include <hip/hip_fp16.h>

#define FIN 128
#define FH 50
#define HSTRIDE 64
#define MAXNB 1024        // supports n <= 131072 with 128-node buckets
#define BSHIFT 7
#define BSIZE 128
#define CAP 3072          // slab capacity per bucket (mean 2046, ~22 sigma margin)
#define PCHUNK 4096       // edges per partition workgroup
#define SRCMASK 0x01FFFFFFu

// -------- CSR build: slab-based two-level counting sort --------

// partition edges into per-bucket slabs: word = (dlocal<<25)|src.
// gcursor[b] (init 0) doubles as reservation cursor and final bucket count.
__global__ __launch_bounds__(256) void partition_kernel(const int* __restrict__ src,
                                                        const int* __restrict__ dst,
                                                        int* __restrict__ gcursor,
                                                        unsigned int* __restrict__ packed,
                                                        int E, int NB) {
    __shared__ int hist[MAXNB];   // phase1: counts; phase3: local cursor
    __shared__ int wbase[MAXNB];
    int t = threadIdx.x;
    int base = blockIdx.x * PCHUNK;
    for (int i = t; i < NB; i += 256) hist[i] = 0;
    __syncthreads();
#pragma unroll 4
    for (int i = 0; i < PCHUNK / 256; i++) {
        int e = base + t + i * 256;
        if (e < E) atomicAdd(&hist[dst[e] >> BSHIFT], 1);
    }
    __syncthreads();
    for (int i = t; i < NB; i += 256) {
        int c = hist[i];
        wbase[i] = c ? atomicAdd(&gcursor[i], c) : 0;
        hist[i] = 0;   // becomes local cursor
    }
    __syncthreads();
#pragma unroll 4
    for (int i = 0; i < PCHUNK / 256; i++) {
        int e = base + t + i * 256;
        if (e < E) {
            unsigned int s = (unsigned int)src[e];
            int d = dst[e];
            int b = d >> BSHIFT;
            int off = atomicAdd(&hist[b], 1);
            packed[(size_t)b * CAP + wbase[b] + off] =
                ((unsigned int)(d & (BSIZE - 1)) << 25) | s;
        }
    }
}

// one WG per bucket: local degree hist -> scan -> rbeg/rend/dinv -> csr fill
__global__ __launch_bounds__(256) void bucket_build_kernel(const unsigned int* __restrict__ packed,
                                                           const int* __restrict__ gcursor,
                                                           int* __restrict__ rbeg,
                                                           int* __restrict__ rend,
                                                           float* __restrict__ dinv,
                                                           int* __restrict__ csr, int n) {
    __shared__ int degl[BSIZE];
    __shared__ int excl[BSIZE];
    __shared__ int lcur[BSIZE];
    int b = blockIdx.x;
    int t = threadIdx.x;
    int nbeg = b << BSHIFT;
    int sbase = b * CAP;
    int cnt = gcursor[b];
    if (t < BSIZE) degl[t] = 0;
    __syncthreads();
    for (int e = t; e < cnt; e += 256)
        atomicAdd(&degl[packed[sbase + e] >> 25], 1);
    __syncthreads();
    int v = (t < BSIZE) ? degl[t] : 0;
    if (t < BSIZE) excl[t] = v;
    __syncthreads();
    for (int off = 1; off < BSIZE; off <<= 1) {
        int add = (t >= off && t < BSIZE) ? excl[t - off] : 0;
        __syncthreads();
        if (t < BSIZE) excl[t] += add;
        __syncthreads();
    }
    if (t < BSIZE) {
        int ex = excl[t] - v;
        int node = nbeg + t;
        if (node < n) {
            rbeg[node] = sbase + ex;
            rend[node] = sbase + ex + v;
            dinv[node] = rsqrtf((float)v + 1.0f);  // +1 = self-loop
        }
        lcur[t] = ex;
    }
    __syncthreads();
    for (int e = t; e < cnt; e += 256) {
        unsigned int w = packed[sbase + e];
        int off = atomicAdd(&lcur[w >> 25], 1);
        csr[sbase + off] = (int)(w & SRCMASK);
    }
}

// -------- dense compute --------

// One-time W transpose + fp16 convert: WT1[c][k] (12.8 KB -> fits the 16 KB
// scalar K$; fp32 W at 25.6 KB thrashed it, costing ~250cyc/s_load misses =
// the R3 55us stall). Transposed layout makes each c's weights contiguous
// packed __half2 -> s_load_dword streams. fp16-W quantization error:
// sqrt(128)*0.09*2.4e-4 ~ 2.5e-4, an order below the fp16-hs error.
__global__ __launch_bounds__(256) void wcvt_kernel(const float* __restrict__ W1,
                                                   const float* __restrict__ W2,
                                                   __half* __restrict__ WT1,
                                                   __half* __restrict__ WT2) {
    int t = blockIdx.x * 256 + threadIdx.x;
    if (t < FIN * FH) {   // 6400
        int k = t / FH, c = t - k * FH;
        WT1[c * FIN + k] = __float2half(W1[t]);
    }
    if (t < FH * FH) {    // 2500
        int k = t / FH, c = t - k * FH;
        WT2[c * FH + k] = __float2half(W2[t]);
    }
}

// hs1[row] = fp16((x[row] @ W1) * dinv[row]), stride 64, pad zeroed.
// One thread per row. Entire x row preloaded into 128 VGPRs (32 dwordx4 all
// in flight once -> no per-iteration VMEM chain). W streamed per c-pair as
// K$-resident s_load_dword of packed half2 (wave-uniform address). 4
// independent FMA chains (c-pair x even/odd k) cover FMA latency at the
// ~1.5 waves/SIMD this grid provides. fmaf(f32,(f32)h16,f32) -> v_fma_mix.
__global__ __launch_bounds__(256) void gemm1_kernel(
    const float* __restrict__ x, const __half* __restrict__ WT,
    const float* __restrict__ dinv, __half* __restrict__ hs1,
    __half* __restrict__ hs2, int n) {
    int t = threadIdx.x;
    if (blockIdx.x == 0) {
        if (t < HSTRIDE)           hs1[((size_t)n << 6) + t] = __float2half(0.f);
        else if (t < 2 * HSTRIDE)  hs2[((size_t)n << 6) + (t - HSTRIDE)] = __float2half(0.f);
    }
    int row = blockIdx.x * 256 + t;
    if (row >= n) return;   // no barriers/shuffles below
    float xr[FIN];
    const float4* xp = (const float4*)(x + (size_t)row * FIN);
#pragma unroll
    for (int i = 0; i < FIN / 4; i++) {
        float4 v = xp[i];
        xr[4 * i]     = v.x;
        xr[4 * i + 1] = v.y;
        xr[4 * i + 2] = v.z;
        xr[4 * i + 3] = v.w;
    }
    float dv = dinv[row];
    __half2* hp = (__half2*)(hs1 + ((size_t)row << 6));
    for (int cp = 0; cp < FH / 2; cp++) {           // 25 c-pairs
        const __half2* w0 = (const __half2*)(WT + (2 * cp) * FIN);      // uniform -> s_load
        const __half2* w1 = (const __half2*)(WT + (2 * cp + 1) * FIN);
        float a0e = 0.f, a0o = 0.f, a1e = 0.f, a1o = 0.f;
#pragma unroll
        for (int k2 = 0; k2 < FIN / 2; k2++) {
            __half2 p0 = w0[k2], p1 = w1[k2];
            a0e = fmaf(xr[2 * k2],     __low2float(p0),  a0e);
            a0o = fmaf(xr[2 * k2 + 1], __high2float(p0), a0o);
            a1e = fmaf(xr[2 * k2],     __low2float(p1),  a1e);
            a1o = fmaf(xr[2 * k2 + 1], __high2float(p1), a1o);
        }
        hp[cp] = __floats2half2_rn((a0e + a0o) * dv, (a1e + a1o) * dv);
    }
#pragma unroll
    for (int c = FH / 2; c < HSTRIDE / 2; c++)      // zero pad cols 50..63
        hp[c] = __floats2half2_rn(0.f, 0.f);
}

// hs2[row] = fp16((h1[row] @ W2) * dinv[row]). Same scheme: h1 row in 50
// VGPRs (float2 loads), WT2 fp16 (5 KB, K$-resident) streamed per c-pair,
// 4 FMA chains. Pad cols 50..63 of regular rows stay garbage (only gather
// lanes >= FH see them; those lanes are never stored).
__global__ __launch_bounds__(256) void gemm2_kernel(
    const float* __restrict__ h1, const __half* __restrict__ WT,
    const float* __restrict__ dinv, __half* __restrict__ hs2, int n) {
    int t = threadIdx.x;
    int row = blockIdx.x * 256 + t;
    if (row >= n) return;
    float xr[FH];
    const float2* xp = (const float2*)(h1 + (size_t)row * FH);
#pragma unroll
    for (int k2 = 0; k2 < FH / 2; k2++) {
        float2 v = xp[k2];
        xr[2 * k2]     = v.x;
        xr[2 * k2 + 1] = v.y;
    }
    float dv = dinv[row];
    __half2* hp = (__half2*)(hs2 + ((size_t)row << 6));
    for (int cp = 0; cp < FH / 2; cp++) {           // 25 c-pairs
        const __half2* w0 = (const __half2*)(WT + (2 * cp) * FH);       // uniform -> s_load
        const __half2* w1 = (const __half2*)(WT + (2 * cp + 1) * FH);
        float a0e = 0.f, a0o = 0.f, a1e = 0.f, a1o = 0.f;
#pragma unroll
        for (int k2 = 0; k2 < FH / 2; k2++) {
            __half2 p0 = w0[k2], p1 = w1[k2];
            a0e = fmaf(xr[2 * k2],     __low2float(p0),  a0e);
            a0o = fmaf(xr[2 * k2 + 1], __high2float(p0), a0o);
            a1e = fmaf(xr[2 * k2],     __low2float(p1),  a1e);
            a1o = fmaf(xr[2 * k2 + 1], __high2float(p1), a1o);
        }
        hp[cp] = __floats2half2_rn((a0e + a0o) * dv, (a1e + a1o) * dv);
    }
}

// one wave per dst row: acc = hs[self] + sum hs[csr[...]]; x16 branchless
// unroll (lanes >= rem hold sentinel n whose hs row is zero), 16 gather
// loads in flight per vmcnt batch. out = relu?(dinv*acc + b), fp32.
__global__ __launch_bounds__(256) void gather_kernel(
    const __half* __restrict__ hs, const int* __restrict__ rbeg,
    const int* __restrict__ rend, const int* __restrict__ csr,
    const float* __restrict__ dinv, const float* __restrict__ b,
    float* __restrict__ out, int n, int do_relu) {
    int wid = blockIdx.x * 4 + (threadIdx.x >> 6);
    int lane = threadIdx.x & 63;
    if (wid >= n) return;
    int beg = rbeg[wid];
    int end = rend[wid];
    float acc = __half2float(hs[((size_t)wid << 6) + lane]);  // self-loop term
    for (int base = beg; base < end; base += 64) {
        int rem = end - base;
        int idx = (lane < rem) ? csr[base + lane] : n;   // n = zero sentinel
        int cnt = rem < 64 ? rem : 64;
        for (int j = 0; j < cnt; j += 16) {
            float v[16];
#pragma unroll
            for (int u = 0; u < 16; u++) {
                int s = __shfl(idx, j + u);
                v[u] = __half2float(hs[((size_t)s << 6) + lane]);
            }
            float s01 = (v[0] + v[1]) + (v[2] + v[3]);
            float s23 = (v[4] + v[5]) + (v[6] + v[7]);
            float s45 = (v[8] + v[9]) + (v[10] + v[11]);
            float s67 = (v[12] + v[13]) + (v[14] + v[15]);
            acc += (s01 + s23) + (s45 + s67);
        }
    }
    if (lane < FH) {
        float o = fmaf(dinv[wid], acc, b[lane]);
        if (do_relu) o = fmaxf(o, 0.f);
        out[(size_t)wid * FH + lane] = o;
    }
}

extern "C" void kernel_launch(void* const* d_in, const int* in_sizes, int n_in,
                              void* d_out, int out_size, void* d_ws, size_t ws_size,
                              hipStream_t stream) {
    const float* x  = (const float*)d_in[0];
    const float* W1 = (const float*)d_in[1];
    const float* b1 = (const float*)d_in[2];
    const float* W2 = (const float*)d_in[3];
    const float* b2 = (const float*)d_in[4];
    const int*   ei = (const int*)d_in[5];

    int n = in_sizes[0] / FIN;   // 100000
    int E = in_sizes[5] / 2;     // 1600000
    const int* src = ei;
    const int* dst = ei + E;
    int NB = (n + BSIZE - 1) >> BSHIFT;   // 782

    char* ws = (char*)d_ws;
    size_t off = 0;
    auto alloc = [&](size_t bytes) {
        void* p = ws + off;
        off = (off + bytes + 511) & ~(size_t)511;
        return p;
    };
    size_t hs_bytes   = (size_t)(n + 1) * HSTRIDE * 2;
    size_t slab_bytes = (size_t)NB * CAP * 4;
    size_t un_bytes   = slab_bytes > hs_bytes ? slab_bytes : hs_bytes;

    int*          gcursor = (int*)alloc((size_t)MAXNB * 4);
    int*          rbeg    = (int*)alloc((size_t)n * 4);
    int*          rend    = (int*)alloc((size_t)n * 4);
    float*        dinv    = (float*)alloc((size_t)n * 4);
    int*          csr     = (int*)alloc(slab_bytes);
    __half*       hs1     = (__half*)alloc(hs_bytes);
    __half*       wt1     = (__half*)alloc((size_t)FIN * FH * 2);   // 12.8 KB
    __half*       wt2     = (__half*)alloc((size_t)FH * FH * 2);    // 5 KB
    void*         un      = alloc(un_bytes);          // packed, then hs2
    unsigned int* packed  = (unsigned int*)un;        // dead after bucket_build
    __half*       hs2     = (__half*)un;              // live after gemm1
    float*        out     = (float*)d_out;            // also layer-1 h buffer

    hipMemsetAsync(gcursor, 0, (size_t)MAXNB * 4, stream);

    wcvt_kernel<<<(FIN * FH + 255) / 256, 256, 0, stream>>>(W1, W2, wt1, wt2);

    int pChunks = (E + PCHUNK - 1) / PCHUNK;   // 391
    partition_kernel<<<pChunks, 256, 0, stream>>>(src, dst, gcursor, packed, E, NB);
    bucket_build_kernel<<<NB, 256, 0, stream>>>(packed, gcursor, rbeg, rend, dinv, csr, n);

    int g1Blocks = (n + 255) / 256;       // 1 thread per row, full K
    int g2Blocks = (n + 255) / 256;       // 1 thread per row
    int gatherBlocks = (n + 3) / 4;       // 4 waves/block, 1 wave/row

    gemm1_kernel<<<g1Blocks, 256, 0, stream>>>(x, wt1, dinv, hs1, hs2, n);
    gather_kernel<<<gatherBlocks, 256, 0, stream>>>(hs1, rbeg, rend, csr, dinv, b1, out, n, 1);
    gemm2_kernel<<<g2Blocks, 256, 0, stream>>>(out, wt2, dinv, hs2, n);
    gather_kernel<<<gatherBlocks, 256, 0, stream>>>(hs2, rbeg, rend, csr, dinv, b2, out, n, 0);
}

// Round 5
// 246.491 us; speedup vs baseline: 1.3153x; 1.3153x over previous
//
#include <hip/hip_runtime.h>
#include <hip/hip_fp16.h>

#define FIN 128
#define FH 50
#define HSTRIDE 64
#define MAXNB 1024        // supports n <= 131072 with 128-node buckets
#define BSHIFT 7
#define BSIZE 128
#define CAP 3072          // slab capacity per bucket (mean 2046, ~22 sigma margin)
#define PCHUNK 4096       // edges per partition workgroup
#define SRCMASK 0x01FFFFFFu

typedef _Float16 f16x8 __attribute__((ext_vector_type(8)));
typedef float f32x4 __attribute__((ext_vector_type(4)));

// -------- CSR build: slab-based two-level counting sort --------

// partition edges into per-bucket slabs: word = (dlocal<<25)|src.
// gcursor[b] (init 0) doubles as reservation cursor and final bucket count.
__global__ __launch_bounds__(256) void partition_kernel(const int* __restrict__ src,
                                                        const int* __restrict__ dst,
                                                        int* __restrict__ gcursor,
                                                        unsigned int* __restrict__ packed,
                                                        int E, int NB) {
    __shared__ int hist[MAXNB];   // phase1: counts; phase3: local cursor
    __shared__ int wbase[MAXNB];
    int t = threadIdx.x;
    int base = blockIdx.x * PCHUNK;
    for (int i = t; i < NB; i += 256) hist[i] = 0;
    __syncthreads();
#pragma unroll 4
    for (int i = 0; i < PCHUNK / 256; i++) {
        int e = base + t + i * 256;
        if (e < E) atomicAdd(&hist[dst[e] >> BSHIFT], 1);
    }
    __syncthreads();
    for (int i = t; i < NB; i += 256) {
        int c = hist[i];
        wbase[i] = c ? atomicAdd(&gcursor[i], c) : 0;
        hist[i] = 0;   // becomes local cursor
    }
    __syncthreads();
#pragma unroll 4
    for (int i = 0; i < PCHUNK / 256; i++) {
        int e = base + t + i * 256;
        if (e < E) {
            unsigned int s = (unsigned int)src[e];
            int d = dst[e];
            int b = d >> BSHIFT;
            int off = atomicAdd(&hist[b], 1);
            packed[(size_t)b * CAP + wbase[b] + off] =
                ((unsigned int)(d & (BSIZE - 1)) << 25) | s;
        }
    }
}

// one WG per bucket: local degree hist -> scan -> rbeg/rend/dinv -> csr fill
__global__ __launch_bounds__(256) void bucket_build_kernel(const unsigned int* __restrict__ packed,
                                                           const int* __restrict__ gcursor,
                                                           int* __restrict__ rbeg,
                                                           int* __restrict__ rend,
                                                           float* __restrict__ dinv,
                                                           int* __restrict__ csr, int n) {
    __shared__ int degl[BSIZE];
    __shared__ int excl[BSIZE];
    __shared__ int lcur[BSIZE];
    int b = blockIdx.x;
    int t = threadIdx.x;
    int nbeg = b << BSHIFT;
    int sbase = b * CAP;
    int cnt = gcursor[b];
    if (t < BSIZE) degl[t] = 0;
    __syncthreads();
    for (int e = t; e < cnt; e += 256)
        atomicAdd(&degl[packed[sbase + e] >> 25], 1);
    __syncthreads();
    int v = (t < BSIZE) ? degl[t] : 0;
    if (t < BSIZE) excl[t] = v;
    __syncthreads();
    for (int off = 1; off < BSIZE; off <<= 1) {
        int add = (t >= off && t < BSIZE) ? excl[t - off] : 0;
        __syncthreads();
        if (t < BSIZE) excl[t] += add;
        __syncthreads();
    }
    if (t < BSIZE) {
        int ex = excl[t] - v;
        int node = nbeg + t;
        if (node < n) {
            rbeg[node] = sbase + ex;
            rend[node] = sbase + ex + v;
            dinv[node] = rsqrtf((float)v + 1.0f);  // +1 = self-loop
        }
        lcur[t] = ex;
    }
    __syncthreads();
    for (int e = t; e < cnt; e += 256) {
        unsigned int w = packed[sbase + e];
        int off = atomicAdd(&lcur[w >> 25], 1);
        csr[sbase + off] = (int)(w & SRCMASK);
    }
}

// -------- dense compute (MFMA) --------

// Pre-swizzle W1/W2 (fp32 [k][c] row-major) into fp16 MFMA B-fragment order
// for v_mfma_f32_16x16x32_f16: linear idx = ((kt*4+ct)*64 + lane)*8 + i,
// element = W[k= kt*32+(lane>>4)*8+i][c= ct*16+(lane&15)], zero-padded
// (c>=50 both; k>=50 for W2). Each wave then loads its B frag as one
// coalesced b128. fp16-W error proven safe in R4 (absmax unchanged 2^-9).
__global__ __launch_bounds__(256) void wcvt_kernel(const float* __restrict__ W1,
                                                   const float* __restrict__ W2,
                                                   _Float16* __restrict__ WF1,
                                                   _Float16* __restrict__ WF2) {
    int idx = blockIdx.x * 256 + threadIdx.x;
    if (idx < 4 * 4 * 64 * 8) {                    // 8192: WF1
        int i = idx & 7, lane = (idx >> 3) & 63, tile = idx >> 9;
        int ct = tile & 3, kt = tile >> 2;
        int k = kt * 32 + ((lane >> 4) << 3) + i;
        int c = ct * 16 + (lane & 15);
        WF1[idx] = (c < FH) ? (_Float16)W1[k * FH + c] : (_Float16)0.f;
    } else if (idx < 8192 + 2 * 4 * 64 * 8) {      // 4096: WF2
        int g = idx - 8192;
        int i = g & 7, lane = (g >> 3) & 63, tile = g >> 9;
        int ct = tile & 3, kt = tile >> 2;
        int k = kt * 32 + ((lane >> 4) << 3) + i;
        int c = ct * 16 + (lane & 15);
        WF2[g] = (k < FH && c < FH) ? (_Float16)W2[k * FH + c] : (_Float16)0.f;
    }
}

// hs1[row] = fp16((x[row] @ W1) * dinv[row]), stride 64. One wave per
// 16-row tile x full 64-col width: 6250 waves = 6/SIMD (R1/R3/R4 all died
// latency-bound at 1.5 waves/SIMD with per-iter LDS/sKcache dep chains).
// x is split hi(fp16)+lo(residual fp16), both MFMA'd -> x effectively fp32;
// only W is fp16 (proven). A frag: row=l&15, k=(l>>4)*8+i; D frag:
// col=l&15, row=(l>>4)*4+reg (verified m89 mapping). Memory floor ~8us.
__global__ __launch_bounds__(256) void gemm1_kernel(
    const float* __restrict__ x, const _Float16* __restrict__ WF,
    const float* __restrict__ dinv, __half* __restrict__ hs1,
    __half* __restrict__ hs2, int n) {
    int t = threadIdx.x;
    if (blockIdx.x == 0) {   // zero sentinel row n of both hs buffers
        if (t < HSTRIDE)           hs1[((size_t)n << 6) + t] = __float2half(0.f);
        else if (t < 2 * HSTRIDE)  hs2[((size_t)n << 6) + (t - HSTRIDE)] = __float2half(0.f);
    }
    int tile = blockIdx.x * 4 + (t >> 6);
    int l = t & 63;
    int mt = (n + 15) >> 4;
    if (tile >= mt) return;   // no barriers below
    int arow = tile * 16 + (l & 15);
    if (arow >= n) arow = n - 1;          // clamp; stores are guarded
    const f16x8* WB = (const f16x8*)WF;
    f32x4 acc[4] = {{0.f,0.f,0.f,0.f},{0.f,0.f,0.f,0.f},
                    {0.f,0.f,0.f,0.f},{0.f,0.f,0.f,0.f}};
#pragma unroll
    for (int kt = 0; kt < 4; kt++) {
        const float* xp = x + (size_t)arow * FIN + kt * 32 + ((l >> 4) << 3);
        float4 v0 = *(const float4*)xp;       // 32B-aligned (offsets mult of 8 floats)
        float4 v1 = *(const float4*)(xp + 4);
        float vs[8] = {v0.x, v0.y, v0.z, v0.w, v1.x, v1.y, v1.z, v1.w};
        f16x8 hi, lo;
#pragma unroll
        for (int i = 0; i < 8; i++) {
            _Float16 h = (_Float16)vs[i];
            hi[i] = h;
            lo[i] = (_Float16)(vs[i] - (float)h);
        }
#pragma unroll
        for (int ct = 0; ct < 4; ct++) {
            f16x8 b = WB[(kt * 4 + ct) * 64 + l];
            acc[ct] = __builtin_amdgcn_mfma_f32_16x16x32_f16(hi, b, acc[ct], 0, 0, 0);
            acc[ct] = __builtin_amdgcn_mfma_f32_16x16x32_f16(lo, b, acc[ct], 0, 0, 0);
        }
    }
    int rbase = tile * 16 + ((l >> 4) << 2);
    float dv[4];
#pragma unroll
    for (int j = 0; j < 4; j++) {
        int r = rbase + j;
        dv[j] = dinv[r < n ? r : 0];
    }
#pragma unroll
    for (int ct = 0; ct < 4; ct++) {
        int col = ct * 16 + (l & 15);
        if (col < FH) {
#pragma unroll
            for (int j = 0; j < 4; j++) {
                int r = rbase + j;
                if (r < n)
                    hs1[((size_t)r << 6) + col] = __float2half(acc[ct][j] * dv[j]);
            }
        }
    }
    // pad cols 50..63 of regular rows stay garbage: gather lanes >= FH read
    // them but never store (lane-local, NaN-safe).
}

// hs2[row] = fp16((h1[row] @ W2) * dinv[row]). Same MFMA structure, KT=2
// (K=50 zero-padded to 64 in both A and the pre-swizzled B). h1 rows are
// 200B-strided: kt=0 uses float2 loads (8B-aligned); kt=1 guarded scalars
// (address-clamped so no OOB read past d_out on the last row).
__global__ __launch_bounds__(256) void gemm2_kernel(
    const float* __restrict__ h1, const _Float16* __restrict__ WF,
    const float* __restrict__ dinv, __half* __restrict__ hs2, int n) {
    int t = threadIdx.x;
    int tile = blockIdx.x * 4 + (t >> 6);
    int l = t & 63;
    int mt = (n + 15) >> 4;
    if (tile >= mt) return;
    int arow = tile * 16 + (l & 15);
    if (arow >= n) arow = n - 1;
    const f16x8* WB = (const f16x8*)WF;
    const float* hp = h1 + (size_t)arow * FH;
    f32x4 acc[4] = {{0.f,0.f,0.f,0.f},{0.f,0.f,0.f,0.f},
                    {0.f,0.f,0.f,0.f},{0.f,0.f,0.f,0.f}};
#pragma unroll
    for (int kt = 0; kt < 2; kt++) {
        int k0 = kt * 32 + ((l >> 4) << 3);
        float vs[8];
        if (kt == 0) {                          // k0 <= 24, all k < 50
            const float2* p2 = (const float2*)(hp + k0);
#pragma unroll
            for (int q = 0; q < 4; q++) {
                float2 v = p2[q];
                vs[2 * q] = v.x;
                vs[2 * q + 1] = v.y;
            }
        } else {                                // k in 32..63: guard k < 50
#pragma unroll
            for (int i = 0; i < 8; i++) {
                int k = k0 + i;
                float v = hp[k < FH ? k : 0];   // clamped addr: no OOB
                vs[i] = (k < FH) ? v : 0.f;
            }
        }
        f16x8 hi, lo;
#pragma unroll
        for (int i = 0; i < 8; i++) {
            _Float16 h = (_Float16)vs[i];
            hi[i] = h;
            lo[i] = (_Float16)(vs[i] - (float)h);
        }
#pragma unroll
        for (int ct = 0; ct < 4; ct++) {
            f16x8 b = WB[(kt * 4 + ct) * 64 + l];
            acc[ct] = __builtin_amdgcn_mfma_f32_16x16x32_f16(hi, b, acc[ct], 0, 0, 0);
            acc[ct] = __builtin_amdgcn_mfma_f32_16x16x32_f16(lo, b, acc[ct], 0, 0, 0);
        }
    }
    int rbase = tile * 16 + ((l >> 4) << 2);
    float dv[4];
#pragma unroll
    for (int j = 0; j < 4; j++) {
        int r = rbase + j;
        dv[j] = dinv[r < n ? r : 0];
    }
#pragma unroll
    for (int ct = 0; ct < 4; ct++) {
        int col = ct * 16 + (l & 15);
        if (col < FH) {
#pragma unroll
            for (int j = 0; j < 4; j++) {
                int r = rbase + j;
                if (r < n)
                    hs2[((size_t)r << 6) + col] = __float2half(acc[ct][j] * dv[j]);
            }
        }
    }
}

// one wave per dst row: acc = hs[self] + sum hs[csr[...]]; x16 branchless
// unroll (lanes >= rem hold sentinel n whose hs row is zero), 16 gather
// loads in flight per vmcnt batch. out = relu?(dinv*acc + b), fp32.
__global__ __launch_bounds__(256) void gather_kernel(
    const __half* __restrict__ hs, const int* __restrict__ rbeg,
    const int* __restrict__ rend, const int* __restrict__ csr,
    const float* __restrict__ dinv, const float* __restrict__ b,
    float* __restrict__ out, int n, int do_relu) {
    int wid = blockIdx.x * 4 + (threadIdx.x >> 6);
    int lane = threadIdx.x & 63;
    if (wid >= n) return;
    int beg = rbeg[wid];
    int end = rend[wid];
    float acc = __half2float(hs[((size_t)wid << 6) + lane]);  // self-loop term
    for (int base = beg; base < end; base += 64) {
        int rem = end - base;
        int idx = (lane < rem) ? csr[base + lane] : n;   // n = zero sentinel
        int cnt = rem < 64 ? rem : 64;
        for (int j = 0; j < cnt; j += 16) {
            float v[16];
#pragma unroll
            for (int u = 0; u < 16; u++) {
                int s = __shfl(idx, j + u);
                v[u] = __half2float(hs[((size_t)s << 6) + lane]);
            }
            float s01 = (v[0] + v[1]) + (v[2] + v[3]);
            float s23 = (v[4] + v[5]) + (v[6] + v[7]);
            float s45 = (v[8] + v[9]) + (v[10] + v[11]);
            float s67 = (v[12] + v[13]) + (v[14] + v[15]);
            acc += (s01 + s23) + (s45 + s67);
        }
    }
    if (lane < FH) {
        float o = fmaf(dinv[wid], acc, b[lane]);
        if (do_relu) o = fmaxf(o, 0.f);
        out[(size_t)wid * FH + lane] = o;
    }
}

extern "C" void kernel_launch(void* const* d_in, const int* in_sizes, int n_in,
                              void* d_out, int out_size, void* d_ws, size_t ws_size,
                              hipStream_t stream) {
    const float* x  = (const float*)d_in[0];
    const float* W1 = (const float*)d_in[1];
    const float* b1 = (const float*)d_in[2];
    const float* W2 = (const float*)d_in[3];
    const float* b2 = (const float*)d_in[4];
    const int*   ei = (const int*)d_in[5];

    int n = in_sizes[0] / FIN;   // 100000
    int E = in_sizes[5] / 2;     // 1600000
    const int* src = ei;
    const int* dst = ei + E;
    int NB = (n + BSIZE - 1) >> BSHIFT;   // 782

    char* ws = (char*)d_ws;
    size_t off = 0;
    auto alloc = [&](size_t bytes) {
        void* p = ws + off;
        off = (off + bytes + 511) & ~(size_t)511;
        return p;
    };
    size_t hs_bytes   = (size_t)(n + 1) * HSTRIDE * 2;
    size_t slab_bytes = (size_t)NB * CAP * 4;
    size_t un_bytes   = slab_bytes > hs_bytes ? slab_bytes : hs_bytes;

    int*          gcursor = (int*)alloc((size_t)MAXNB * 4);
    int*          rbeg    = (int*)alloc((size_t)n * 4);
    int*          rend    = (int*)alloc((size_t)n * 4);
    float*        dinv    = (float*)alloc((size_t)n * 4);
    int*          csr     = (int*)alloc(slab_bytes);
    __half*       hs1     = (__half*)alloc(hs_bytes);
    _Float16*     wf1     = (_Float16*)alloc((size_t)8192 * 2);   // 16 KB B-frags
    _Float16*     wf2     = (_Float16*)alloc((size_t)4096 * 2);   // 8 KB
    void*         un      = alloc(un_bytes);          // packed, then hs2
    unsigned int* packed  = (unsigned int*)un;        // dead after bucket_build
    __half*       hs2     = (__half*)un;              // live after gemm1
    float*        out     = (float*)d_out;            // also layer-1 h buffer

    hipMemsetAsync(gcursor, 0, (size_t)MAXNB * 4, stream);

    wcvt_kernel<<<(8192 + 4096 + 255) / 256, 256, 0, stream>>>(W1, W2, wf1, wf2);

    int pChunks = (E + PCHUNK - 1) / PCHUNK;   // 391
    partition_kernel<<<pChunks, 256, 0, stream>>>(src, dst, gcursor, packed, E, NB);
    bucket_build_kernel<<<NB, 256, 0, stream>>>(packed, gcursor, rbeg, rend, dinv, csr, n);

    int mt = (n + 15) / 16;               // 6250 row-tiles
    int gBlocks = (mt + 3) / 4;           // 4 waves/block, 1 tile/wave
    int gatherBlocks = (n + 3) / 4;       // 4 waves/block, 1 wave/row

    gemm1_kernel<<<gBlocks, 256, 0, stream>>>(x, wf1, dinv, hs1, hs2, n);
    gather_kernel<<<gatherBlocks, 256, 0, stream>>>(hs1, rbeg, rend, csr, dinv, b1, out, n, 1);
    gemm2_kernel<<<gBlocks, 256, 0, stream>>>(out, wf2, dinv, hs2, n);
    gather_kernel<<<gatherBlocks, 256, 0, stream>>>(hs2, rbeg, rend, csr, dinv, b2, out, n, 0);
}